// Round 6
// baseline (970.365 us; speedup 1.0000x reference)
//
#include <hip/hip_runtime.h>
#include <hip/hip_bf16.h>

// SequenceStateSpace: delta = sigmoid(seq@Wd^T + bd); value = seq@Wv^T + bv;
// out_t = (1-delta_t)*out_{t-1} + delta_t*value_t
//
// Round 6: f16 delta/value intermediates (halves GEMM write + scan read
// traffic; error ~5e-4 << 7.8e-3 observed floor) and single-pass
// decoupled-lookback scan (aggregate -> publish -> lookback -> apply),
// replacing the 3-pass chunked scan. GEMM structure unchanged from round 5.

typedef _Float16 f16;
typedef _Float16 f16x4 __attribute__((ext_vector_type(4)));
typedef _Float16 f16x8 __attribute__((ext_vector_type(8)));
typedef float    f32x4 __attribute__((ext_vector_type(4)));

#define NB  8
#define NT  4096
#define ND  1024
#define NM  (NB*NT)      // 32768 rows
#define KK  1024         // f16-hi only

#define CT  64           // scan chunk length
#define NCH (NT/CT)      // 64 chunks per batch

// ---------------- workspace layout (bytes) ----------------
#define OFF_AP     0UL           // Ap  [NM][KK] f16      : 67108864
#define OFF_BP     67108864UL    // Bp  [2048][ND] f16    :  4194304
#define OFF_DLT    71303168UL    // Dlt [NM][ND] f16      : 67108864
#define OFF_VAL    138412032UL   // Val [NM][ND] f16      : 67108864
#define OFF_AARR   205520896UL   // Aarr [512][ND] f32    :  2097152
#define OFF_SARR   207618048UL   // Sarr [512][ND] f32    :  2097152
#define OFF_FLAG   209715200UL   // flags [512] u32

#define GLOAD_LDS16(gp, lp)                                                          \
  __builtin_amdgcn_global_load_lds(                                                  \
      (const __attribute__((address_space(1))) void*)(gp),                           \
      (__attribute__((address_space(3))) void*)(lp), 16, 0, 0)

#define MEMFENCE asm volatile("" ::: "memory")
#define BARRIER() do { MEMFENCE; __builtin_amdgcn_s_barrier(); MEMFENCE; } while (0)
#define WAITV2() asm volatile("s_waitcnt vmcnt(2)" ::: "memory")
#define WAITV0() asm volatile("s_waitcnt vmcnt(0)" ::: "memory")

// ---------------- pass 0: zero lookback flags (ws is poisoned each call) ----------
__global__ void k_zero_flags(unsigned* __restrict__ flags) {
  flags[threadIdx.x] = 0u;   // 512 threads, 1 block
}

// ---------------- pass 1a: seq -> f16 ----------------
__global__ void k_convert_seq(const float* __restrict__ src, f16* __restrict__ Ap) {
  const long n8 = (long)NM * ND / 8;
  long i = (long)blockIdx.x * blockDim.x + threadIdx.x;
  const long stride = (long)gridDim.x * blockDim.x;
  for (; i < n8; i += stride) {
    const float4 v0 = *(const float4*)(src + i * 8);
    const float4 v1 = *(const float4*)(src + i * 8 + 4);
    f16x8 h;
    h[0] = (f16)v0.x; h[1] = (f16)v0.y; h[2] = (f16)v0.z; h[3] = (f16)v0.w;
    h[4] = (f16)v1.x; h[5] = (f16)v1.y; h[6] = (f16)v1.z; h[7] = (f16)v1.w;
    *((f16x8*)Ap + i) = h;
  }
}

// ---------------- pass 1b: W_delta/W_value -> f16 (concat rows) ----------------
__global__ void k_convert_w(const float* __restrict__ Wd, const float* __restrict__ Wv,
                            f16* __restrict__ Bp) {
  const long i = (long)blockIdx.x * blockDim.x + threadIdx.x;  // 262144 threads
  const int n = (int)(i >> 7);
  const int k8 = ((int)i & 127) * 8;
  const float* row = (n < ND) ? (Wd + (long)n * ND) : (Wv + (long)(n - ND) * ND);
  const float4 v0 = *(const float4*)(row + k8);
  const float4 v1 = *(const float4*)(row + k8 + 4);
  f16x8 h;
  h[0] = (f16)v0.x; h[1] = (f16)v0.y; h[2] = (f16)v0.z; h[3] = (f16)v0.w;
  h[4] = (f16)v1.x; h[5] = (f16)v1.y; h[6] = (f16)v1.z; h[7] = (f16)v1.w;
  *(f16x8*)(Bp + (long)n * ND + k8) = h;
}

// ---------------- pass 2: GEMM, 256x256 tile, counted-vmcnt 4-phase ----------------
#define LDS_A(c) ((c) * 65536)
#define LDS_B(c) ((c) * 65536 + 32768)

__global__ __launch_bounds__(512, 2) void k_gemm(
    const f16* __restrict__ Ap, const f16* __restrict__ Bp,
    const float* __restrict__ bd, const float* __restrict__ bv,
    f16* __restrict__ Dlt, f16* __restrict__ Val) {
  __shared__ char smem[131072];

  const int t = threadIdx.x;
  const int w = t >> 6, lane = t & 63;
  const int wr = w >> 2, wc = w & 3;           // 2(M) x 4(N) waves; wave out = 128x64
  const int l15 = lane & 15, l4 = lane >> 4;

  // XCD-aware bijective swizzle (nwg=1024, %8==0)
  const int bid = blockIdx.x;
  const int sw = (bid & 7) * 128 + (bid >> 3);
  const int bm = sw >> 3, bn = sw & 7;
  const long m0 = (long)bm * 256;
  const int n0 = bn * 256;

  f32x4 acc[8][4] = {};

  // staging: half-tile = 128 rows x 64 cols f16 = 16KB; 2 x 16B loads/thread
  const int rl0 = t >> 3;                      // rows 0..63
  const int rl1 = 64 + (t >> 3);               // rows 64..127
  const int c16_0 = (t & 7) ^ (rl0 & 7);       // pre-swizzled source col16
  const int c16_1 = (t & 7) ^ (rl1 & 7);

  auto stageA = [&](int kt, int h, int c) {
    const f16* s0 = Ap + (m0 + h * 128 + rl0) * (long)KK + kt * 64 + c16_0 * 8;
    const f16* s1 = Ap + (m0 + h * 128 + rl1) * (long)KK + kt * 64 + c16_1 * 8;
    char* base = smem + LDS_A(c) + h * 16384 + w * 1024;
    GLOAD_LDS16(s0, base);
    GLOAD_LDS16(s1, base + 8192);
  };
  auto stageB = [&](int kt, int h, int c) {
    const f16* s0 = Bp + (long)(n0 + h * 128 + rl0) * ND + kt * 64 + c16_0 * 8;
    const f16* s1 = Bp + (long)(n0 + h * 128 + rl1) * ND + kt * 64 + c16_1 * 8;
    char* base = smem + LDS_B(c) + h * 16384 + w * 1024;
    GLOAD_LDS16(s0, base);
    GLOAD_LDS16(s1, base + 8192);
  };

  f16x8 aF[8], bF[2];
  auto readA = [&](int c, int k) {
#pragma unroll
    for (int mf = 0; mf < 8; ++mf) {
      const int row = wr * 128 + mf * 16 + l15;
      const int c16 = (k * 4 + l4) ^ (row & 7);
      aF[mf] = *(const f16x8*)(smem + LDS_A(c) + row * 128 + c16 * 16);
    }
  };
  auto readB = [&](int c, int k, int nh) {
#pragma unroll
    for (int nfl = 0; nfl < 2; ++nfl) {
      const int row = nh * 128 + wc * 32 + nfl * 16 + l15;
      const int c16 = (k * 4 + l4) ^ (row & 7);
      bF[nfl] = *(const f16x8*)(smem + LDS_B(c) + row * 128 + c16 * 16);
    }
  };
  // Swapped operands: D = transpose -> lane l15 holds m, (l4*4+r) holds n.
  auto mfmaQ = [&](int nh) {
    __builtin_amdgcn_s_setprio(1);
#pragma unroll
    for (int mf = 0; mf < 8; ++mf)
#pragma unroll
      for (int nfl = 0; nfl < 2; ++nfl)
        acc[mf][nh * 2 + nfl] = __builtin_amdgcn_mfma_f32_16x16x32_f16(
            bF[nfl], aF[mf], acc[mf][nh * 2 + nfl], 0, 0, 0);
    __builtin_amdgcn_s_setprio(0);
  };

  auto tile = [&](int c, int ktNext, bool pf) {
    // phase 0
    if (pf) stageA(ktNext, 0, c ^ 1);
    readA(c, 0); readB(c, 0, 0);
    BARRIER();
    mfmaQ(0);
    if (pf) { WAITV2(); } else { WAITV0(); }   // B1 of current tile landed
    BARRIER();
    // phase 1
    if (pf) stageA(ktNext, 1, c ^ 1);
    readB(c, 0, 1);
    BARRIER();
    mfmaQ(1);
    BARRIER();
    // phase 2
    if (pf) stageB(ktNext, 0, c ^ 1);
    readA(c, 1); readB(c, 1, 0);
    BARRIER();
    mfmaQ(0);
    BARRIER();
    // phase 3
    if (pf) stageB(ktNext, 1, c ^ 1);
    readB(c, 1, 1);
    BARRIER();
    mfmaQ(1);
    if (pf) { WAITV2(); } else { WAITV0(); }   // A0,A1,B0 of next tile landed
    BARRIER();
  };

  // prologue: stage tile 0 into buf0
  stageA(0, 0, 0); stageA(0, 1, 0); stageB(0, 0, 0); stageB(0, 1, 0);
  WAITV2();
  BARRIER();

  for (int i = 0; i < 8; ++i) {               // 16 K-tiles of 64 (K=1024)
    tile(0, 2 * i + 1, true);
    tile(1, 2 * i + 2, i < 7);
  }

  // epilogue: bias (+sigmoid) -> f16, 8B stores along n
  const bool isDelta = (n0 < ND);              // block-uniform
#pragma unroll
  for (int nf = 0; nf < 4; ++nf) {
    const int nb = n0 + (nf >> 1) * 128 + wc * 32 + (nf & 1) * 16 + l4 * 4;
    const float4 bias = *(const float4*)(isDelta ? (bd + nb) : (bv + (nb - ND)));
    f16* const dst = isDelta ? (Dlt + nb) : (Val + (nb - ND));
#pragma unroll
    for (int mf = 0; mf < 8; ++mf) {
      const long m = m0 + wr * 128 + mf * 16 + l15;
      f32x4 x = acc[mf][nf];
      x[0] += bias.x; x[1] += bias.y; x[2] += bias.z; x[3] += bias.w;
      if (isDelta) {
#pragma unroll
        for (int r = 0; r < 4; ++r) x[r] = 1.0f / (1.0f + __expf(-x[r]));
      }
      f16x4 h;
      h[0] = (f16)x[0]; h[1] = (f16)x[1]; h[2] = (f16)x[2]; h[3] = (f16)x[3];
      *(f16x4*)(dst + m * ND) = h;
    }
  }
}

// ---------------- pass 3: single-pass decoupled-lookback scan ----------------
// Block (b,c): local aggregate over chunk -> publish (release flag) ->
// lookback over predecessors (acquire) -> apply + write out f32.
// Grid = 512 blocks, 256 thr, 0 LDS -> all co-resident; publish precedes
// spin -> deadlock-free under any dispatch order.
__global__ __launch_bounds__(256) void k_scan(
    const f16* __restrict__ Dlt, const f16* __restrict__ Val,
    float* __restrict__ out, float* __restrict__ Aarr, float* __restrict__ Sarr,
    unsigned* __restrict__ flags) {
  const int bid = blockIdx.x;                  // 512 = 8b * 64c
  const int c = bid & 63, b = bid >> 6;
  const int d = threadIdx.x * 4;
  const long base = ((long)b * NT + (long)c * CT) * ND + d;

  // local aggregate: a = prod(1-dl), s = chunk response from zero init
  float4 a = make_float4(1.f, 1.f, 1.f, 1.f);
  float4 s = make_float4(0.f, 0.f, 0.f, 0.f);
#pragma unroll 4
  for (int tt = 0; tt < CT; ++tt) {
    const f16x4 dh = *(const f16x4*)(Dlt + base + (long)tt * ND);
    const f16x4 vh = *(const f16x4*)(Val + base + (long)tt * ND);
    const float d0 = (float)dh[0], d1 = (float)dh[1], d2 = (float)dh[2], d3 = (float)dh[3];
    const float o0 = 1.f - d0, o1 = 1.f - d1, o2 = 1.f - d2, o3 = 1.f - d3;
    a.x *= o0; a.y *= o1; a.z *= o2; a.w *= o3;
    s.x = o0 * s.x + d0 * (float)vh[0];
    s.y = o1 * s.y + d1 * (float)vh[1];
    s.z = o2 * s.z + d2 * (float)vh[2];
    s.w = o3 * s.w + d3 * (float)vh[3];
  }
  const long o = (long)bid * ND + d;
  *(float4*)(Aarr + o) = a;
  *(float4*)(Sarr + o) = s;
  __syncthreads();                             // all payload written
  __threadfence();                             // device-scope release fence
  if (threadIdx.x == 0)
    __hip_atomic_store(flags + bid, 1u, __ATOMIC_RELEASE, __HIP_MEMORY_SCOPE_AGENT);

  // lookback: prefix entering chunk c (aggregate-only, Merrill-style)
  float4 A = make_float4(1.f, 1.f, 1.f, 1.f);
  float4 S = make_float4(0.f, 0.f, 0.f, 0.f);
  for (int p = c - 1; p >= 0; --p) {
    const unsigned* fp = flags + (b << 6) + p;
    while (__hip_atomic_load(fp, __ATOMIC_ACQUIRE, __HIP_MEMORY_SCOPE_AGENT) == 0u) {}
    const long po = (long)((b << 6) + p) * ND + d;
    const float4 ap = *(const float4*)(Aarr + po);
    const float4 sp = *(const float4*)(Sarr + po);
    S.x += A.x * sp.x; S.y += A.y * sp.y; S.z += A.z * sp.z; S.w += A.w * sp.w;
    A.x *= ap.x; A.y *= ap.y; A.z *= ap.z; A.w *= ap.w;
  }

  // apply with true init (chunk data L2/L3-warm from pass 1)
  float4 st = S;
#pragma unroll 4
  for (int tt = 0; tt < CT; ++tt) {
    const long idx = base + (long)tt * ND;
    const f16x4 dh = *(const f16x4*)(Dlt + idx);
    const f16x4 vh = *(const f16x4*)(Val + idx);
    const float d0 = (float)dh[0], d1 = (float)dh[1], d2 = (float)dh[2], d3 = (float)dh[3];
    st.x = (1.f - d0) * st.x + d0 * (float)vh[0];
    st.y = (1.f - d1) * st.y + d1 * (float)vh[1];
    st.z = (1.f - d2) * st.z + d2 * (float)vh[2];
    st.w = (1.f - d3) * st.w + d3 * (float)vh[3];
    *(float4*)(out + idx) = st;
  }
}

extern "C" void kernel_launch(void* const* d_in, const int* in_sizes, int n_in,
                              void* d_out, int out_size, void* d_ws, size_t ws_size,
                              hipStream_t stream) {
  const float* seq = (const float*)d_in[0];
  const float* Wd  = (const float*)d_in[1];
  const float* bd  = (const float*)d_in[2];
  const float* Wv  = (const float*)d_in[3];
  const float* bv  = (const float*)d_in[4];
  float* out = (float*)d_out;

  char* ws = (char*)d_ws;
  f16*      Ap    = (f16*)(ws + OFF_AP);
  f16*      Bp    = (f16*)(ws + OFF_BP);
  f16*      Dlt   = (f16*)(ws + OFF_DLT);
  f16*      Val   = (f16*)(ws + OFF_VAL);
  float*    Aarr  = (float*)(ws + OFF_AARR);
  float*    Sarr  = (float*)(ws + OFF_SARR);
  unsigned* flags = (unsigned*)(ws + OFF_FLAG);

  hipLaunchKernelGGL(k_zero_flags,  dim3(1),    dim3(512), 0, stream, flags);
  hipLaunchKernelGGL(k_convert_seq, dim3(2048), dim3(256), 0, stream, seq, Ap);
  hipLaunchKernelGGL(k_convert_w,   dim3(1024), dim3(256), 0, stream, Wd, Wv, Bp);
  hipLaunchKernelGGL(k_gemm, dim3(1024), dim3(512), 0, stream, Ap, Bp, bd, bv, Dlt, Val);
  hipLaunchKernelGGL(k_scan, dim3(512), dim3(256), 0, stream, Dlt, Val, out, Aarr, Sarr, flags);
}